// Round 14
// baseline (411.674 us; speedup 1.0000x reference)
//
#include <hip/hip_runtime.h>
#include <hip/hip_fp16.h>
#include <math.h>

#define N_NODES 50000
#define N_EDGES 1000000
#define F_IN    165
#define KP1     176                         // F_IN padded to 16
#define HID     128
#define HEADS   4
#define F_OUT   32
#define NEG_SLOPE 0.2f
#define NB_SCAN  ((N_NODES + 255) / 256)   // 196 scan blocks
#define NPART    8                          // dst partitions (= XCDs)
#define PART_SZ  (N_NODES / NPART)          // 6250, exact
#define SCHUNKS  256                        // edge chunks for scatter

typedef _Float16 half4v __attribute__((ext_vector_type(4)));
typedef float    f32x4  __attribute__((ext_vector_type(4)));

// ===== prep: features fp32 -> fp16 padded [N][KP1] ==========================
__global__ __launch_bounds__(256) void cvt_features(const float* __restrict__ X,
                                                    __half* __restrict__ Xh) {
    const long long i = (long long)blockIdx.x * 256 + threadIdx.x;
    if (i >= (long long)N_NODES * KP1) return;
    const int n = (int)(i / KP1);
    const int k = (int)(i - (long long)n * KP1);
    Xh[i] = (k < F_IN) ? __float2half_rn(X[(long long)n * F_IN + k])
                       : __float2half_rn(0.f);
}

// ===== prep: pack W[K][128] fp32 into MFMA B-fragment order fp16 =============
__global__ __launch_bounds__(256) void pack_w(const float* __restrict__ W,
                                              __half* __restrict__ Wp,
                                              int K, int ksteps) {
    const int idx = blockIdx.x * 256 + threadIdx.x;   // (kt*8+ct)*64 + lane
    if (idx >= ksteps * 8 * 64) return;
    const int lane = idx & 63;
    const int tile = idx >> 6;
    const int ct = tile & 7;
    const int kt = tile >> 3;
    const int col = ct * 16 + (lane & 15);
    const int k0 = kt * 16 + 4 * (lane >> 4);
#pragma unroll
    for (int i = 0; i < 4; ++i) {
        const int k = k0 + i;
        Wp[(size_t)idx * 4 + i] = (k < K) ? __float2half_rn(W[(size_t)k * HID + col])
                                          : __float2half_rn(0.f);
    }
}

// ===== MFMA GEMM + fused attention logits (verbatim R9, passed) ==============
template <int KSTEPS, int KP>
__global__ __launch_bounds__(256) void gemm_mfma(const __half* __restrict__ Xh,
                                                 const __half* __restrict__ Wp,
                                                 const float* __restrict__ al,
                                                 const float* __restrict__ ar,
                                                 __half* __restrict__ feat,
                                                 float* __restrict__ el,
                                                 float* __restrict__ er) {
    const int tid  = threadIdx.x;
    const int wav  = tid >> 6;
    const int lane = tid & 63;
    const int base = blockIdx.x * 64 + wav * 16;     // 16-row slice per wave
    if (base >= N_NODES) return;
    const int lr = lane & 15;                         // row (A) / col (B,D)
    const int lq = lane >> 4;                         // k-quad / row-quad

    f32x4 acc[8];
#pragma unroll
    for (int ct = 0; ct < 8; ++ct) acc[ct] = (f32x4){0.f, 0.f, 0.f, 0.f};

    const __half* arow = Xh + (size_t)(base + lr) * KP + 4 * lq;
    for (int kt = 0; kt < KSTEPS; ++kt) {
        const half4v a = *reinterpret_cast<const half4v*>(arow + kt * 16);
        const __half* bp = Wp + ((size_t)kt * 8 * 64 + lane) * 4;
#pragma unroll
        for (int ct = 0; ct < 8; ++ct) {
            const half4v b = *reinterpret_cast<const half4v*>(bp + (size_t)ct * 256);
            acc[ct] = __builtin_amdgcn_mfma_f32_16x16x16f16(a, b, acc[ct], 0, 0, 0);
        }
    }

    float alv[8], arv[8];
#pragma unroll
    for (int ct = 0; ct < 8; ++ct) {
        const int h = ct >> 1;
        const int f = (ct & 1) * 16 + lr;
        alv[ct] = al[h * F_OUT + f];
        arv[ct] = ar[h * F_OUT + f];
    }

#pragma unroll
    for (int i = 0; i < 4; ++i) {
        const int node = base + 4 * lq + i;           // D row = 4*lq + i
#pragma unroll
        for (int ct = 0; ct < 8; ++ct)
            feat[(size_t)node * HID + ct * 16 + lr] = __float2half_rn(acc[ct][i]);
#pragma unroll
        for (int h = 0; h < 4; ++h) {
            float pl = acc[2 * h][i] * alv[2 * h] + acc[2 * h + 1][i] * alv[2 * h + 1];
            float pr = acc[2 * h][i] * arv[2 * h] + acc[2 * h + 1][i] * arv[2 * h + 1];
            pl += __shfl_xor(pl, 1); pr += __shfl_xor(pr, 1);
            pl += __shfl_xor(pl, 2); pr += __shfl_xor(pr, 2);
            pl += __shfl_xor(pl, 4); pr += __shfl_xor(pr, 4);
            pl += __shfl_xor(pl, 8); pr += __shfl_xor(pr, 8);
            if (lr == 0) {
                el[node * HEADS + h] = pl;
                er[node * HEADS + h] = pr;
            }
        }
    }
}

// ================= CSR build (once per launch, reused by both layers) ========

__global__ __launch_bounds__(256) void zero_counts(int* __restrict__ counts) {
    const int i = blockIdx.x * 256 + threadIdx.x;
    if (i < N_NODES) counts[i] = 0;
}

__global__ __launch_bounds__(256) void hist_dst(const int* __restrict__ dst,
                                                int* __restrict__ counts) {
    const int e = blockIdx.x * 256 + threadIdx.x;
    if (e < N_EDGES) atomicAdd(&counts[dst[e]], 1);
}

__global__ __launch_bounds__(256) void scan_local(const int* __restrict__ counts,
                                                  int* __restrict__ rowptr,
                                                  int* __restrict__ blockSums) {
    __shared__ int tmp[256];
    const int i = blockIdx.x * 256 + threadIdx.x;
    const int v = (i < N_NODES) ? counts[i] : 0;
    tmp[threadIdx.x] = v;
    __syncthreads();
#pragma unroll
    for (int off = 1; off < 256; off <<= 1) {
        int t = (threadIdx.x >= off) ? tmp[threadIdx.x - off] : 0;
        __syncthreads();
        tmp[threadIdx.x] += t;
        __syncthreads();
    }
    if (i < N_NODES) rowptr[i] = tmp[threadIdx.x] - v;
    if (threadIdx.x == 255) blockSums[blockIdx.x] = tmp[255];
}

__global__ __launch_bounds__(256) void scan_sums(int* __restrict__ blockSums) {
    __shared__ int tmp[256];
    const int v = (threadIdx.x < NB_SCAN) ? blockSums[threadIdx.x] : 0;
    tmp[threadIdx.x] = v;
    __syncthreads();
#pragma unroll
    for (int off = 1; off < 256; off <<= 1) {
        int t = (threadIdx.x >= off) ? tmp[threadIdx.x - off] : 0;
        __syncthreads();
        tmp[threadIdx.x] += t;
        __syncthreads();
    }
    if (threadIdx.x < NB_SCAN) blockSums[threadIdx.x] = tmp[threadIdx.x] - v;
}

__global__ __launch_bounds__(256) void add_offsets(int* __restrict__ rowptr,
                                                   const int* __restrict__ blockSums,
                                                   int* __restrict__ cursor) {
    const int i = blockIdx.x * 256 + threadIdx.x;
    if (i < N_NODES) {
        const int r = rowptr[i] + blockSums[blockIdx.x];
        rowptr[i] = r;
        cursor[i] = r;
    }
    if (i == 0) rowptr[N_NODES] = N_EDGES;
}

__global__ __launch_bounds__(256) void scatter_csr_part(const int* __restrict__ src,
                                                        const int* __restrict__ dst,
                                                        int* __restrict__ cursor,
                                                        int* __restrict__ csr_src) {
    const int part  = blockIdx.x & (NPART - 1);
    const int chunk = blockIdx.x >> 3;
    constexpr int CE = (N_EDGES + SCHUNKS - 1) / SCHUNKS;   // 3907
    const int e0 = chunk * CE;
    const int e1 = min(e0 + CE, N_EDGES);
    for (int e = e0 + threadIdx.x; e < e1; e += 256) {
        const int d = dst[e];
        if (d / PART_SZ == part) {
            const int pos = atomicAdd(&cursor[d], 1);
            csr_src[pos] = src[e];
        }
    }
}

// ===== GAT aggregation: one wave per (node, head), head <-> XCD affinity =====
// Grid: bid = nb*4 + h; block = 4 waves = 4 nodes (4nb..4nb+3), all head h.
// Round-robin bid->XCD means XCD x only runs heads x&3 -> its feat working set
// is one 64B column-slice of each row = 3.2MB (L2-resident). Lane = 32*ep + c:
// 32-lane groups process edges of parity ep (2 edges per instruction stream —
// no per-edge instruction duplication); lane's feature = h*32 + c (2B gather;
// a group's gather = one 64B line). No barriers, no LDS; combine via
// shfl_xor(32). exp in-loop (w-tables proven net-negative, R8/R12).
__global__ __launch_bounds__(256) void gat_aggregate_h(const int* __restrict__ rowptr,
                                                       const int* __restrict__ csr_src,
                                                       const float* __restrict__ el,
                                                       const float* __restrict__ er,
                                                       const __half* __restrict__ feat,
                                                       __half* __restrict__ outh) {
    const int bid = blockIdx.x;
    const int h   = bid & 3;
    const int d   = (bid >> 2) * 4 + (threadIdx.x >> 6);
    if (d >= N_NODES) return;
    const int lane = threadIdx.x & 63;
    const int ep   = lane >> 5;          // edge-parity group 0/1
    const int c    = lane & 31;          // feature within head
    const int start = rowptr[d], end = rowptr[d + 1];
    const float erd = er[d * HEADS + h];
    const __half* __restrict__ fcol = feat + h * 32 + c;   // + s*128 per edge

    float denom = 0.f, acc = 0.f;
    for (int chunk = start; chunk < end; chunk += 64) {
        const int cnt = min(64, end - chunk);
        const int idx = chunk + lane;
        const int sv = csr_src[idx < end ? idx : start];
        int t = 0;
        for (; t + 8 <= cnt; t += 8) {   // group ep: edges t+ep, +2, +4, +6
            const unsigned s0 = (unsigned)__shfl(sv, t + ep);
            const unsigned s1 = (unsigned)__shfl(sv, t + 2 + ep);
            const unsigned s2 = (unsigned)__shfl(sv, t + 4 + ep);
            const unsigned s3 = (unsigned)__shfl(sv, t + 6 + ep);
            const float e0 = el[s0 * 4u + h];
            const float e1 = el[s1 * 4u + h];
            const float e2 = el[s2 * 4u + h];
            const float e3 = el[s3 * 4u + h];
            const __half q0 = fcol[s0 * 128u];
            const __half q1 = fcol[s1 * 128u];
            const __half q2 = fcol[s2 * 128u];
            const __half q3 = fcol[s3 * 128u];
            float v0 = e0 + erd; v0 = fmaxf(v0, NEG_SLOPE * v0);
            float v1 = e1 + erd; v1 = fmaxf(v1, NEG_SLOPE * v1);
            float v2 = e2 + erd; v2 = fmaxf(v2, NEG_SLOPE * v2);
            float v3 = e3 + erd; v3 = fmaxf(v3, NEG_SLOPE * v3);
            const float x0 = __expf(v0);
            const float x1 = __expf(v1);
            const float x2 = __expf(v2);
            const float x3 = __expf(v3);
            denom += (x0 + x1) + (x2 + x3);
            acc += __half2float(q0) * x0 + __half2float(q1) * x1
                 + __half2float(q2) * x2 + __half2float(q3) * x3;
        }
        for (; t < cnt; t += 2) {        // masked tail
            const int e = t + ep;
            const int ei = e < cnt ? e : 0;        // keep shfl index in range
            const unsigned s0 = (unsigned)__shfl(sv, ei);
            const float e0 = el[s0 * 4u + h];
            const __half q0 = fcol[s0 * 128u];
            float v0 = e0 + erd; v0 = fmaxf(v0, NEG_SLOPE * v0);
            float x0 = __expf(v0);
            if (e >= cnt) x0 = 0.f;                // group-1 idle on odd tail
            denom += x0;
            acc += __half2float(q0) * x0;
        }
    }

    // combine the two edge-parity groups (no LDS, no barrier)
    acc   += __shfl_xor(acc, 32);
    denom += __shfl_xor(denom, 32);

    const float inv = 1.f / fmaxf(denom, 1e-9f);
    const float hv = fmaxf(acc * inv, 0.f);
    if (ep == 0)
        outh[(size_t)d * HID + h * 32 + c] = __float2half_rn(hv);
}

// ---- MLP heads: wave per node, reads fp16 h2 (verbatim R11, passed) ---------
__global__ __launch_bounds__(256) void heads_kernel(const __half* __restrict__ hbuf,
                                                    const float* __restrict__ Wc1,
                                                    const float* __restrict__ bc1,
                                                    const float* __restrict__ Wc2,
                                                    const float* __restrict__ bc2,
                                                    const float* __restrict__ Wf1,
                                                    const float* __restrict__ bf1,
                                                    const float* __restrict__ Wf2,
                                                    const float* __restrict__ bf2,
                                                    float* __restrict__ out) {
    const int wid = (blockIdx.x * 256 + threadIdx.x) >> 6;
    if (wid >= N_NODES) return;
    const int lane = threadIdx.x & 63;
    const __half2 x2 = ((const __half2*)hbuf)[(size_t)wid * 64 + lane];
    const float2 x = __half22float2(x2);
    float ac[10], af[10];
#pragma unroll
    for (int o = 0; o < 10; ++o) {
        ac[o] = x.x * Wc1[(lane * 2) * 10 + o] + x.y * Wc1[(lane * 2 + 1) * 10 + o];
        af[o] = x.x * Wf1[(lane * 2) * 10 + o] + x.y * Wf1[(lane * 2 + 1) * 10 + o];
    }
#pragma unroll
    for (int off = 32; off >= 1; off >>= 1) {
#pragma unroll
        for (int o = 0; o < 10; ++o) {
            ac[o] += __shfl_xor(ac[o], off);
            af[o] += __shfl_xor(af[o], off);
        }
    }
    if (lane == 0) {
        float pc = bc2[0], pf = bf2[0];
#pragma unroll
        for (int o = 0; o < 10; ++o) {
            pc += fmaxf(ac[o] + bc1[o], 0.f) * Wc2[o];
            pf += fmaxf(af[o] + bf1[o], 0.f) * Wf2[o];
        }
        out[wid] = pc;
        out[N_NODES + wid] = 1.0f / (1.0f + __expf(-pf));
    }
}

extern "C" void kernel_launch(void* const* d_in, const int* in_sizes, int n_in,
                              void* d_out, int out_size, void* d_ws, size_t ws_size,
                              hipStream_t stream) {
    const float* features = (const float*)d_in[0];
    const int*   src      = (const int*)d_in[1];
    const int*   dst      = (const int*)d_in[2];
    const float* W1  = (const float*)d_in[3];
    const float* al1 = (const float*)d_in[4];
    const float* ar1 = (const float*)d_in[5];
    const float* W2  = (const float*)d_in[6];
    const float* al2 = (const float*)d_in[7];
    const float* ar2 = (const float*)d_in[8];
    const float* Wc1 = (const float*)d_in[9];
    const float* bc1 = (const float*)d_in[10];
    const float* Wc2 = (const float*)d_in[11];
    const float* bc2 = (const float*)d_in[12];
    const float* Wf1 = (const float*)d_in[13];
    const float* bf1 = (const float*)d_in[14];
    const float* Wf2 = (const float*)d_in[15];
    const float* bf2 = (const float*)d_in[16];
    float* out = (float*)d_out;

    // workspace layout (verbatim R9):
    // Xh[N*176] | feat[N*128] | hbuf[N*128] | Wp1 | Wp2
    // | el[4N] f32 | er[4N] f32 | counts | rowptr | cursor | blockSums | csr_src
    __half* Xh   = (__half*)d_ws;
    __half* feat = Xh + (size_t)N_NODES * KP1;
    __half* hbuf = feat + (size_t)N_NODES * HID;
    __half* Wp1  = hbuf + (size_t)N_NODES * HID;
    __half* Wp2  = Wp1 + 11 * 8 * 64 * 4;
    float*  el   = (float*)(Wp2 + 8 * 8 * 64 * 4);
    float*  er   = el + (size_t)N_NODES * HEADS;
    int* counts    = (int*)(er + (size_t)N_NODES * HEADS);
    int* rowptr    = counts + N_NODES;
    int* cursor    = rowptr + N_NODES + 1;
    int* blockSums = cursor + N_NODES;
    int* csr_src   = blockSums + 256;

    const int nodeWaveBlocks = (N_NODES * 64 + 255) / 256;   // 12500
    const int aggBlocks      = ((N_NODES + 3) / 4) * 4;      // 50000 (nb*4+h)
    const int edgeBlocks     = (N_EDGES + 255) / 256;        // 3907
    const int gemmBlocks     = (N_NODES + 63) / 64;          // 782
    const int scatterBlocks  = SCHUNKS * NPART;              // 2048
    const int cvtBlocks      = (int)(((long long)N_NODES * KP1 + 255) / 256);

    // ---------- prep: fp16 conversions + W fragment packing -----------------
    cvt_features<<<cvtBlocks, 256, 0, stream>>>(features, Xh);
    pack_w<<<(11 * 8 * 64 + 255) / 256, 256, 0, stream>>>(W1, Wp1, F_IN, 11);
    pack_w<<<(8 * 8 * 64 + 255) / 256, 256, 0, stream>>>(W2, Wp2, HID, 8);

    // ---------- CSR build (dst-sorted incidence), reused by both layers ------
    zero_counts<<<NB_SCAN, 256, 0, stream>>>(counts);
    hist_dst<<<edgeBlocks, 256, 0, stream>>>(dst, counts);
    scan_local<<<NB_SCAN, 256, 0, stream>>>(counts, rowptr, blockSums);
    scan_sums<<<1, 256, 0, stream>>>(blockSums);
    add_offsets<<<NB_SCAN, 256, 0, stream>>>(rowptr, blockSums, cursor);
    scatter_csr_part<<<scatterBlocks, 256, 0, stream>>>(src, dst, cursor, csr_src);

    // ---------- layer 1 ----------
    gemm_mfma<11, KP1><<<gemmBlocks, 256, 0, stream>>>(Xh, Wp1, al1, ar1,
                                                       feat, el, er);
    gat_aggregate_h<<<aggBlocks, 256, 0, stream>>>(rowptr, csr_src, el, er,
                                                   feat, hbuf);

    // ---------- layer 2 ----------
    gemm_mfma<8, HID><<<gemmBlocks, 256, 0, stream>>>(hbuf, Wp2, al2, ar2,
                                                      feat, el, er);
    gat_aggregate_h<<<aggBlocks, 256, 0, stream>>>(rowptr, csr_src, el, er,
                                                   feat, hbuf);

    // ---------- heads ----------
    heads_kernel<<<nodeWaveBlocks, 256, 0, stream>>>(hbuf, Wc1, bc1, Wc2, bc2,
                                                     Wf1, bf1, Wf2, bf2, out);
}

// Round 15
// 289.061 us; speedup vs baseline: 1.4242x; 1.4242x over previous
//
#include <hip/hip_runtime.h>
#include <hip/hip_fp16.h>
#include <math.h>

#define N_NODES 50000
#define N_EDGES 1000000
#define F_IN    165
#define KP1     176                         // F_IN padded to 16
#define HID     128
#define HEADS   4
#define F_OUT   32
#define NEG_SLOPE 0.2f
#define NB_SCAN  ((N_NODES + 255) / 256)   // 196 scan blocks
#define NPART    8                          // dst partitions (= XCDs)
#define PART_SZ  (N_NODES / NPART)          // 6250, exact
#define SCHUNKS  256                        // edge chunks for scatter

typedef _Float16 half4v __attribute__((ext_vector_type(4)));
typedef float    f32x4  __attribute__((ext_vector_type(4)));

// ===== prep: features fp32 -> fp16 padded [N][KP1] ==========================
__global__ __launch_bounds__(256) void cvt_features(const float* __restrict__ X,
                                                    __half* __restrict__ Xh) {
    const long long i = (long long)blockIdx.x * 256 + threadIdx.x;
    if (i >= (long long)N_NODES * KP1) return;
    const int n = (int)(i / KP1);
    const int k = (int)(i - (long long)n * KP1);
    Xh[i] = (k < F_IN) ? __float2half_rn(X[(long long)n * F_IN + k])
                       : __float2half_rn(0.f);
}

// ===== prep: pack W[K][128] fp32 into MFMA B-fragment order fp16 =============
__global__ __launch_bounds__(256) void pack_w(const float* __restrict__ W,
                                              __half* __restrict__ Wp,
                                              int K, int ksteps) {
    const int idx = blockIdx.x * 256 + threadIdx.x;   // (kt*8+ct)*64 + lane
    if (idx >= ksteps * 8 * 64) return;
    const int lane = idx & 63;
    const int tile = idx >> 6;
    const int ct = tile & 7;
    const int kt = tile >> 3;
    const int col = ct * 16 + (lane & 15);
    const int k0 = kt * 16 + 4 * (lane >> 4);
#pragma unroll
    for (int i = 0; i < 4; ++i) {
        const int k = k0 + i;
        Wp[(size_t)idx * 4 + i] = (k < K) ? __float2half_rn(W[(size_t)k * HID + col])
                                          : __float2half_rn(0.f);
    }
}

// ===== MFMA GEMM + fused attention logits (verbatim R9, passed) ==============
template <int KSTEPS, int KP>
__global__ __launch_bounds__(256) void gemm_mfma(const __half* __restrict__ Xh,
                                                 const __half* __restrict__ Wp,
                                                 const float* __restrict__ al,
                                                 const float* __restrict__ ar,
                                                 __half* __restrict__ feat,
                                                 float* __restrict__ el,
                                                 float* __restrict__ er) {
    const int tid  = threadIdx.x;
    const int wav  = tid >> 6;
    const int lane = tid & 63;
    const int base = blockIdx.x * 64 + wav * 16;     // 16-row slice per wave
    if (base >= N_NODES) return;
    const int lr = lane & 15;                         // row (A) / col (B,D)
    const int lq = lane >> 4;                         // k-quad / row-quad

    f32x4 acc[8];
#pragma unroll
    for (int ct = 0; ct < 8; ++ct) acc[ct] = (f32x4){0.f, 0.f, 0.f, 0.f};

    const __half* arow = Xh + (size_t)(base + lr) * KP + 4 * lq;
    for (int kt = 0; kt < KSTEPS; ++kt) {
        const half4v a = *reinterpret_cast<const half4v*>(arow + kt * 16);
        const __half* bp = Wp + ((size_t)kt * 8 * 64 + lane) * 4;
#pragma unroll
        for (int ct = 0; ct < 8; ++ct) {
            const half4v b = *reinterpret_cast<const half4v*>(bp + (size_t)ct * 256);
            acc[ct] = __builtin_amdgcn_mfma_f32_16x16x16f16(a, b, acc[ct], 0, 0, 0);
        }
    }

    float alv[8], arv[8];
#pragma unroll
    for (int ct = 0; ct < 8; ++ct) {
        const int h = ct >> 1;
        const int f = (ct & 1) * 16 + lr;
        alv[ct] = al[h * F_OUT + f];
        arv[ct] = ar[h * F_OUT + f];
    }

#pragma unroll
    for (int i = 0; i < 4; ++i) {
        const int node = base + 4 * lq + i;           // D row = 4*lq + i
#pragma unroll
        for (int ct = 0; ct < 8; ++ct)
            feat[(size_t)node * HID + ct * 16 + lr] = __float2half_rn(acc[ct][i]);
#pragma unroll
        for (int h = 0; h < 4; ++h) {
            float pl = acc[2 * h][i] * alv[2 * h] + acc[2 * h + 1][i] * alv[2 * h + 1];
            float pr = acc[2 * h][i] * arv[2 * h] + acc[2 * h + 1][i] * arv[2 * h + 1];
            pl += __shfl_xor(pl, 1); pr += __shfl_xor(pr, 1);
            pl += __shfl_xor(pl, 2); pr += __shfl_xor(pr, 2);
            pl += __shfl_xor(pl, 4); pr += __shfl_xor(pr, 4);
            pl += __shfl_xor(pl, 8); pr += __shfl_xor(pr, 8);
            if (lr == 0) {
                el[node * HEADS + h] = pl;
                er[node * HEADS + h] = pr;
            }
        }
    }
}

// ================= CSR build (once per launch, reused by both layers) ========

__global__ __launch_bounds__(256) void zero_counts(int* __restrict__ counts) {
    const int i = blockIdx.x * 256 + threadIdx.x;
    if (i < N_NODES) counts[i] = 0;
}

__global__ __launch_bounds__(256) void hist_dst(const int* __restrict__ dst,
                                                int* __restrict__ counts) {
    const int e = blockIdx.x * 256 + threadIdx.x;
    if (e < N_EDGES) atomicAdd(&counts[dst[e]], 1);
}

__global__ __launch_bounds__(256) void scan_local(const int* __restrict__ counts,
                                                  int* __restrict__ rowptr,
                                                  int* __restrict__ blockSums) {
    __shared__ int tmp[256];
    const int i = blockIdx.x * 256 + threadIdx.x;
    const int v = (i < N_NODES) ? counts[i] : 0;
    tmp[threadIdx.x] = v;
    __syncthreads();
#pragma unroll
    for (int off = 1; off < 256; off <<= 1) {
        int t = (threadIdx.x >= off) ? tmp[threadIdx.x - off] : 0;
        __syncthreads();
        tmp[threadIdx.x] += t;
        __syncthreads();
    }
    if (i < N_NODES) rowptr[i] = tmp[threadIdx.x] - v;
    if (threadIdx.x == 255) blockSums[blockIdx.x] = tmp[255];
}

__global__ __launch_bounds__(256) void scan_sums(int* __restrict__ blockSums) {
    __shared__ int tmp[256];
    const int v = (threadIdx.x < NB_SCAN) ? blockSums[threadIdx.x] : 0;
    tmp[threadIdx.x] = v;
    __syncthreads();
#pragma unroll
    for (int off = 1; off < 256; off <<= 1) {
        int t = (threadIdx.x >= off) ? tmp[threadIdx.x - off] : 0;
        __syncthreads();
        tmp[threadIdx.x] += t;
        __syncthreads();
    }
    if (threadIdx.x < NB_SCAN) blockSums[threadIdx.x] = tmp[threadIdx.x] - v;
}

__global__ __launch_bounds__(256) void add_offsets(int* __restrict__ rowptr,
                                                   const int* __restrict__ blockSums,
                                                   int* __restrict__ cursor) {
    const int i = blockIdx.x * 256 + threadIdx.x;
    if (i < N_NODES) {
        const int r = rowptr[i] + blockSums[blockIdx.x];
        rowptr[i] = r;
        cursor[i] = r;
    }
    if (i == 0) rowptr[N_NODES] = N_EDGES;
}

__global__ __launch_bounds__(256) void scatter_csr_part(const int* __restrict__ src,
                                                        const int* __restrict__ dst,
                                                        int* __restrict__ cursor,
                                                        int* __restrict__ csr_src) {
    const int part  = blockIdx.x & (NPART - 1);
    const int chunk = blockIdx.x >> 3;
    constexpr int CE = (N_EDGES + SCHUNKS - 1) / SCHUNKS;   // 3907
    const int e0 = chunk * CE;
    const int e1 = min(e0 + CE, N_EDGES);
    for (int e = e0 + threadIdx.x; e < e1; e += 256) {
        const int d = dst[e];
        if (d / PART_SZ == part) {
            const int pos = atomicAdd(&cursor[d], 1);
            csr_src[pos] = src[e];
        }
    }
}

// ===== fused GAT aggregation (R9 structure, masked x8 batching) ==============
// Wave per node; full 128-feature rows (4B/lane); exp in loop (w-tables proven
// net-negative). ONE change vs R9: 8 edges per batch -> 16 independent gathers
// in flight (R8's proven wave-uniform masking; OOB edges get weight 0 and a
// clamped-but-valid gather row). FUSE_HEADS: layer-2 computes MLP heads from
// in-register h2.
template <bool FUSE_HEADS>
__global__ __launch_bounds__(256) void gat_aggregate(const int* __restrict__ rowptr,
                                                     const int* __restrict__ csr_src,
                                                     const float* __restrict__ el,
                                                     const float* __restrict__ er,
                                                     const __half* __restrict__ feat,
                                                     __half* __restrict__ outh,
                                                     const float* __restrict__ Wc1,
                                                     const float* __restrict__ bc1,
                                                     const float* __restrict__ Wc2,
                                                     const float* __restrict__ bc2,
                                                     const float* __restrict__ Wf1,
                                                     const float* __restrict__ bf1,
                                                     const float* __restrict__ Wf2,
                                                     const float* __restrict__ bf2,
                                                     float* __restrict__ out) {
    const int d = (blockIdx.x * 256 + threadIdx.x) >> 6;
    if (d >= N_NODES) return;
    const int lane = threadIdx.x & 63;
    const int h = lane >> 4;
    const int start = rowptr[d], end = rowptr[d + 1];
    const float erd = er[d * HEADS + h];
    const __half2* __restrict__ feat2 = (const __half2*)feat;   // row stride 64

    float denom = 0.f, ax = 0.f, ay = 0.f;
    for (int chunk = start; chunk < end; chunk += 64) {
        const int cnt = min(64, end - chunk);
        const int idx = chunk + lane;
        const int sv = csr_src[idx < end ? idx : start];
        for (int i = 0; i < cnt; i += 8) {
            int s[8];
            float ev[8];
            __half2 q[8];
#pragma unroll
            for (int j = 0; j < 8; ++j)
                s[j] = __shfl(sv, (i + j) < 64 ? (i + j) : 0);
#pragma unroll
            for (int j = 0; j < 8; ++j)
                ev[j] = el[s[j] * HEADS + h];
#pragma unroll
            for (int j = 0; j < 8; ++j)
                q[j] = feat2[(size_t)s[j] * 64 + lane];
            float x[8];
#pragma unroll
            for (int j = 0; j < 8; ++j) {
                float v = ev[j] + erd;
                v = v > 0.f ? v : NEG_SLOPE * v;
                x[j] = __expf(v);
                if (i + j >= cnt) x[j] = 0.f;      // wave-uniform mask
            }
#pragma unroll
            for (int j = 0; j < 8; ++j) {
                const float2 f = __half22float2(q[j]);
                denom += x[j];
                ax += f.x * x[j];
                ay += f.y * x[j];
            }
        }
    }
    const float inv = 1.f / fmaxf(denom, 1e-9f);
    const float hx = fmaxf(ax * inv, 0.f);
    const float hy = fmaxf(ay * inv, 0.f);

    if (!FUSE_HEADS) {
        ((__half2*)outh)[(size_t)d * 64 + lane] = __floats2half2_rn(hx, hy);
        return;
    }

    float ac[10], af[10];
#pragma unroll
    for (int o = 0; o < 10; ++o) {
        ac[o] = hx * Wc1[(lane * 2) * 10 + o] + hy * Wc1[(lane * 2 + 1) * 10 + o];
        af[o] = hx * Wf1[(lane * 2) * 10 + o] + hy * Wf1[(lane * 2 + 1) * 10 + o];
    }
#pragma unroll
    for (int off = 32; off >= 1; off >>= 1) {
#pragma unroll
        for (int o = 0; o < 10; ++o) {
            ac[o] += __shfl_xor(ac[o], off);
            af[o] += __shfl_xor(af[o], off);
        }
    }
    if (lane == 0) {
        float pc = bc2[0], pf = bf2[0];
#pragma unroll
        for (int o = 0; o < 10; ++o) {
            pc += fmaxf(ac[o] + bc1[o], 0.f) * Wc2[o];
            pf += fmaxf(af[o] + bf1[o], 0.f) * Wf2[o];
        }
        out[d] = pc;
        out[N_NODES + d] = 1.0f / (1.0f + __expf(-pf));
    }
}

extern "C" void kernel_launch(void* const* d_in, const int* in_sizes, int n_in,
                              void* d_out, int out_size, void* d_ws, size_t ws_size,
                              hipStream_t stream) {
    const float* features = (const float*)d_in[0];
    const int*   src      = (const int*)d_in[1];
    const int*   dst      = (const int*)d_in[2];
    const float* W1  = (const float*)d_in[3];
    const float* al1 = (const float*)d_in[4];
    const float* ar1 = (const float*)d_in[5];
    const float* W2  = (const float*)d_in[6];
    const float* al2 = (const float*)d_in[7];
    const float* ar2 = (const float*)d_in[8];
    const float* Wc1 = (const float*)d_in[9];
    const float* bc1 = (const float*)d_in[10];
    const float* Wc2 = (const float*)d_in[11];
    const float* bc2 = (const float*)d_in[12];
    const float* Wf1 = (const float*)d_in[13];
    const float* bf1 = (const float*)d_in[14];
    const float* Wf2 = (const float*)d_in[15];
    const float* bf2 = (const float*)d_in[16];
    float* out = (float*)d_out;

    // workspace layout (verbatim R9):
    // Xh[N*176] | feat[N*128] | hbuf[N*128] | Wp1 | Wp2
    // | el[4N] f32 | er[4N] f32 | counts | rowptr | cursor | blockSums | csr_src
    __half* Xh   = (__half*)d_ws;
    __half* feat = Xh + (size_t)N_NODES * KP1;
    __half* hbuf = feat + (size_t)N_NODES * HID;
    __half* Wp1  = hbuf + (size_t)N_NODES * HID;
    __half* Wp2  = Wp1 + 11 * 8 * 64 * 4;
    float*  el   = (float*)(Wp2 + 8 * 8 * 64 * 4);
    float*  er   = el + (size_t)N_NODES * HEADS;
    int* counts    = (int*)(er + (size_t)N_NODES * HEADS);
    int* rowptr    = counts + N_NODES;
    int* cursor    = rowptr + N_NODES + 1;
    int* blockSums = cursor + N_NODES;
    int* csr_src   = blockSums + 256;

    const int nodeWaveBlocks = (N_NODES * 64 + 255) / 256;   // 12500
    const int edgeBlocks     = (N_EDGES + 255) / 256;        // 3907
    const int gemmBlocks     = (N_NODES + 63) / 64;          // 782
    const int scatterBlocks  = SCHUNKS * NPART;              // 2048
    const int cvtBlocks      = (int)(((long long)N_NODES * KP1 + 255) / 256);

    // ---------- prep: fp16 conversions + W fragment packing -----------------
    cvt_features<<<cvtBlocks, 256, 0, stream>>>(features, Xh);
    pack_w<<<(11 * 8 * 64 + 255) / 256, 256, 0, stream>>>(W1, Wp1, F_IN, 11);
    pack_w<<<(8 * 8 * 64 + 255) / 256, 256, 0, stream>>>(W2, Wp2, HID, 8);

    // ---------- CSR build (dst-sorted incidence), reused by both layers ------
    zero_counts<<<NB_SCAN, 256, 0, stream>>>(counts);
    hist_dst<<<edgeBlocks, 256, 0, stream>>>(dst, counts);
    scan_local<<<NB_SCAN, 256, 0, stream>>>(counts, rowptr, blockSums);
    scan_sums<<<1, 256, 0, stream>>>(blockSums);
    add_offsets<<<NB_SCAN, 256, 0, stream>>>(rowptr, blockSums, cursor);
    scatter_csr_part<<<scatterBlocks, 256, 0, stream>>>(src, dst, cursor, csr_src);

    // ---------- layer 1 ----------
    gemm_mfma<11, KP1><<<gemmBlocks, 256, 0, stream>>>(Xh, Wp1, al1, ar1,
                                                       feat, el, er);
    gat_aggregate<false><<<nodeWaveBlocks, 256, 0, stream>>>(
        rowptr, csr_src, el, er, feat, hbuf,
        Wc1, bc1, Wc2, bc2, Wf1, bf1, Wf2, bf2, out);

    // ---------- layer 2 (heads fused into aggregation epilogue) ----------
    gemm_mfma<8, HID><<<gemmBlocks, 256, 0, stream>>>(hbuf, Wp2, al2, ar2,
                                                      feat, el, er);
    gat_aggregate<true><<<nodeWaveBlocks, 256, 0, stream>>>(
        rowptr, csr_src, el, er, feat, nullptr,
        Wc1, bc1, Wc2, bc2, Wf1, bf1, Wf2, bf2, out);
}